// Round 1
// baseline (136.706 us; speedup 1.0000x reference)
//
#include <hip/hip_runtime.h>
#include <stdint.h>

// Binary morphology reduction of the erosion/skeleton reference.
// x==1 predicate is sufficient: erode test (conv>=ksum) with unit weights and
// values <=1 is "all support pixels ==1"; update b &= ~dilate(mask).

typedef unsigned long long u64;

#define WIDTH   1024
#define HEIGHT  1024
#define NIMG    16
#define WPR     16     // uint64 words per row (1024 bits)
#define TH      64     // tile height in rows
#define TWW     4      // tile width in words (256 px)
#define RROWS   96     // region rows = TH + 2*16 halo
#define RWORDS  6      // region words = TWW + 1 word halo each side (64 >= 16)
#define PR      98     // padded rows  (zero ring)
#define PW      8      // padded words (zero ring)

// ---------------- phase 1: binarize + bit-pack via wave ballot ----------------
__global__ __launch_bounds__(256) void pack_kernel(const float* __restrict__ x,
                                                   u64* __restrict__ packed) {
    int rowg = blockIdx.x;              // global row: 0 .. NIMG*HEIGHT-1
    int tid  = threadIdx.x;
    int wv   = tid >> 6;
    int lane = tid & 63;
    const float* base = x + (size_t)rowg * WIDTH + wv * 256;
    u64* pbase = packed + (size_t)rowg * WPR + wv * 4;
    #pragma unroll
    for (int j = 0; j < 4; ++j) {
        float f = base[j * 64 + lane];
        u64 m = __ballot(f > 0.5f);     // bit i = pixel (base + j*64 + i), LSB-first
        if (lane == 0) pbase[j] = m;
    }
}

// ---------------- bitwise shift helpers (LSB = leftmost pixel) ----------------
// value at pixel x-1 (dc=-1): (c << 1) | (west >> 63)
// value at pixel x+1 (dc=+1): (c >> 1) | (east << 63)
__device__ __forceinline__ u64 hrow_and(const u64* Ar, int w, int rowbits) {
    u64 res = ~0ULL;
    u64 c = Ar[w];
    if (rowbits & 1) res &= (c << 1) | (Ar[w - 1] >> 63);  // kernel col 0 -> dc=-1
    if (rowbits & 2) res &= c;
    if (rowbits & 4) res &= (c >> 1) | (Ar[w + 1] << 63);  // kernel col 2 -> dc=+1
    return res;
}
__device__ __forceinline__ u64 hrow_or(const u64* Ar, int w, int rowbits) {
    u64 res = 0;
    u64 c = Ar[w];
    if (rowbits & 1) res |= (c >> 1) | (Ar[w + 1] << 63);  // col 0 -> sample x+1
    if (rowbits & 2) res |= c;
    if (rowbits & 4) res |= (c << 1) | (Ar[w - 1] >> 63);  // col 2 -> sample x-1
    return res;
}

// erosion: M[p] = AND_{(dr,dc) in S} B[p + (dr,dc)]
template <int KM>
__device__ __forceinline__ u64 erode_cell(const u64 (*A)[PW], int r, int w) {
    u64 res = ~0ULL;
    if ((KM >> 0) & 7) res &= hrow_and(A[r - 1], w, (KM >> 0) & 7); // kr=0 -> dr=-1
    if ((KM >> 3) & 7) res &= hrow_and(A[r    ], w, (KM >> 3) & 7);
    if ((KM >> 6) & 7) res &= hrow_and(A[r + 1], w, (KM >> 6) & 7); // kr=2 -> dr=+1
    return res;
}
// dilation (reflected kernel): V[p] = OR_{(dr,dc) in S} M[p - (dr,dc)]
template <int KM>
__device__ __forceinline__ u64 dilate_cell(const u64 (*A)[PW], int r, int w) {
    u64 res = 0;
    if ((KM >> 0) & 7) res |= hrow_or(A[r + 1], w, (KM >> 0) & 7);  // kr=0 -> sample r+1
    if ((KM >> 3) & 7) res |= hrow_or(A[r    ], w, (KM >> 3) & 7);
    if ((KM >> 6) & 7) res |= hrow_or(A[r - 1], w, (KM >> 6) & 7);  // kr=2 -> sample r-1
    return res;
}

template <int KM>
__device__ __forceinline__ void morph_step(u64 (&B)[PR][PW], u64 (&M)[PR][PW],
                                           u64 (&O)[PR][PW], int tid) {
    for (int cell = tid; cell < RROWS * RWORDS; cell += 256) {
        int r = 1 + cell / RWORDS;
        int w = 1 + cell % RWORDS;
        u64 m = erode_cell<KM>(B, r, w);
        M[r][w] = m;
        O[r][w] |= m;
    }
    __syncthreads();
    for (int cell = tid; cell < RROWS * RWORDS; cell += 256) {
        int r = 1 + cell / RWORDS;
        int w = 1 + cell % RWORDS;
        B[r][w] &= ~dilate_cell<KM>(M, r, w);
    }
    __syncthreads();
}

// ---------------- phase 2: fused 8-step morphology + isolated-point ----------
__global__ __launch_bounds__(256) void morph_kernel(const u64* __restrict__ packed,
                                                    float* __restrict__ out) {
    __shared__ u64 B[PR][PW];
    __shared__ u64 M[PR][PW];
    __shared__ u64 O[PR][PW];
    int tid = threadIdx.x;
    int tx = blockIdx.x, ty = blockIdx.y, img = blockIdx.z;

    // zero everything (pads stay zero forever -> zero boundary condition)
    {
        u64* bf = &B[0][0]; u64* mf = &M[0][0]; u64* of = &O[0][0];
        for (int i = tid; i < PR * PW; i += 256) { bf[i] = 0; mf[i] = 0; of[i] = 0; }
    }
    __syncthreads();

    // load packed region (tile +/- 16 rows, +/- 1 word) with image-bounds clip
    const u64* pimg = packed + (size_t)img * HEIGHT * WPR;
    for (int cell = tid; cell < RROWS * RWORDS; cell += 256) {
        int r = cell / RWORDS, w = cell % RWORDS;
        int gy = ty * TH - 16 + r;
        int gw = tx * TWW - 1 + w;
        if (gy >= 0 && gy < HEIGHT && gw >= 0 && gw < WPR)
            B[r + 1][w + 1] = pimg[(size_t)gy * WPR + gw];
    }
    __syncthreads();

    // the 8 fixed structuring elements, bit (kr*3+kc)
    morph_step<511>(B, M, O, tid);  // all ones
    morph_step<438>(B, M, O, tid);  // cols 1,2
    morph_step< 63>(B, M, O, tid);  // rows 0,1
    morph_step<432>(B, M, O, tid);  // r in {1,2}, c in {1,2}
    morph_step<146>(B, M, O, tid);  // col 1
    morph_step< 56>(B, M, O, tid);  // row 1
    morph_step< 18>(B, M, O, tid);  // c=1, r in {0,1}
    morph_step< 24>(B, M, O, tid);  // r=1, c in {0,1}

    // final: out = (3x3 popcount of O == 1), via carry-save (ones, sticky twos)
    {
        int w = 2 + (tid & 3);        // tile words are local 2..5
        int r = 17 + (tid >> 2);      // tile rows  are local 17..80
        u64 ones = 0, twos = 0;
        #pragma unroll
        for (int dr = -1; dr <= 1; ++dr) {
            const u64* Ar = O[r + dr];
            u64 c  = Ar[w];
            u64 wv = (c << 1) | (Ar[w - 1] >> 63);
            u64 ev = (c >> 1) | (Ar[w + 1] << 63);
            twos |= ones & wv; ones ^= wv;
            twos |= ones & c;  ones ^= c;
            twos |= ones & ev; ones ^= ev;
        }
        M[r][w] = ones & ~twos;       // reuse M as result buffer
    }
    __syncthreads();

    // write float output, coalesced: each row = 256 consecutive floats/block
    float* obase = out + ((size_t)img * HEIGHT + (size_t)ty * TH) * WIDTH + tx * (TWW * 64);
    int w = 2 + (tid >> 6);
    int bit = tid & 63;
    for (int row = 0; row < TH; ++row) {
        u64 word = M[17 + row][w];    // LDS broadcast within each wave
        obase[(size_t)row * WIDTH + tid] = (float)((word >> bit) & 1ULL);
    }
}

extern "C" void kernel_launch(void* const* d_in, const int* in_sizes, int n_in,
                              void* d_out, int out_size, void* d_ws, size_t ws_size,
                              hipStream_t stream) {
    const float* x = (const float*)d_in[0];
    float* out = (float*)d_out;
    u64* packed = (u64*)d_ws;   // NIMG*HEIGHT*WPR*8 = 2 MiB

    hipLaunchKernelGGL(pack_kernel, dim3(NIMG * HEIGHT), dim3(256), 0, stream, x, packed);
    hipLaunchKernelGGL(morph_kernel,
                       dim3(WIDTH / (TWW * 64), HEIGHT / TH, NIMG), dim3(256), 0, stream,
                       packed, out);
}

// Round 3
// 125.901 us; speedup vs baseline: 1.0858x; 1.0858x over previous
//
#include <hip/hip_runtime.h>
#include <stdint.h>

// Binary morphology reduction of the erosion/skeleton reference.
// All 8 structuring elements are axis-aligned rectangles -> separable
// erode (AND) / dilate (OR): horizontal bit-shift pass + vertical pass.
// Full-width tiles (16 u64 words = 1024 px), 64-row strips, halo 16 rows.

typedef unsigned long long u64;

#define WIDTH   1024
#define HEIGHT  1024
#define NIMG    16
#define WPR     16          // u64 words per image row
#define TH      64          // tile rows per block
#define PR      98          // padded rows: 96 region rows + zero ring
#define PW      18          // padded words: 16 + zero ring
#define NTHR    512

// ---------------- phase 1: binarize + bit-pack via wave ballot ----------------
__global__ __launch_bounds__(256) void pack_kernel(const float* __restrict__ x,
                                                   u64* __restrict__ packed) {
    int rowg = blockIdx.x;
    int tid  = threadIdx.x;
    int wv   = tid >> 6;
    int lane = tid & 63;
    const float* base = x + (size_t)rowg * WIDTH + wv * 256;
    u64* pbase = packed + (size_t)rowg * WPR + wv * 4;
    #pragma unroll
    for (int j = 0; j < 4; ++j) {
        float f = base[j * 64 + lane];
        u64 m = __ballot(f > 0.5f);      // bit i (LSB-first) = pixel base+j*64+i
        if (lane == 0) pbase[j] = m;
    }
}

// ---------------- bit-parallel separable helpers (LSB = leftmost pixel) -------
// erode horizontal: AND over kernel cols in CM (bit0: dc=-1, bit1: 0, bit2: +1)
template <int CM>
__device__ __forceinline__ u64 hand(const u64* Ar, int w) {
    u64 c = Ar[w], res = ~0ULL;
    if (CM & 2) res &= c;
    if (CM & 1) res &= (c << 1) | (Ar[w - 1] >> 63);   // sample x-1
    if (CM & 4) res &= (c >> 1) | (Ar[w + 1] << 63);   // sample x+1
    return res;
}
// dilate horizontal (reflected kernel): OR, offsets negated
template <int CM>
__device__ __forceinline__ u64 hor(const u64* Ar, int w) {
    u64 c = Ar[w], res = 0;
    if (CM & 2) res |= c;
    if (CM & 1) res |= (c >> 1) | (Ar[w + 1] << 63);   // sample x+1
    if (CM & 4) res |= (c << 1) | (Ar[w - 1] >> 63);   // sample x-1
    return res;
}
template <int RM>
__device__ __forceinline__ u64 vand(const u64 (*A)[PW], int r, int w) {
    u64 res = ~0ULL;
    if (RM & 1) res &= A[r - 1][w];
    if (RM & 2) res &= A[r][w];
    if (RM & 4) res &= A[r + 1][w];
    return res;
}
template <int RM>
__device__ __forceinline__ u64 vor(const u64 (*A)[PW], int r, int w) {
    u64 res = 0;
    if (RM & 1) res |= A[r + 1][w];
    if (RM & 2) res |= A[r][w];
    if (RM & 4) res |= A[r - 1][w];
    return res;
}

// Apply f(r,w) to all cells within row-radius R of the tile (tile = padded
// rows 17..80), full width (padded words 1..16). Barrier afterwards.
template <int R, typename F>
__device__ __forceinline__ void forcells(F f) {
    for (int idx = threadIdx.x; idx < (TH + 2 * R) * WPR; idx += NTHR) {
        int r = 17 - R + (idx >> 4);
        int w = 1 + (idx & 15);
        f(r, w);
    }
    __syncthreads();
}

// One skeleton step: M = erode(B,S); O |= M; B &= ~dilate(M, reflect(S)).
// RM/CM: row/col presence masks. HR/MR/DHR/BR: shrinking row radii.
template <int RM, int CM, int HR, int MR, int DHR, int BR, bool DIL>
__device__ __forceinline__ void morph_step(u64 (&B)[PR][PW], u64 (&T)[PR][PW],
                                           u64 (&M)[PR][PW], u64 (&O)[PR][PW]) {
    // ---- erode ----
    if (CM != 2 && RM != 2) {
        forcells<HR>([&](int r, int w) { T[r][w] = hand<CM>(B[r], w); });
        forcells<MR>([&](int r, int w) {
            u64 m = vand<RM>(T, r, w); M[r][w] = m; O[r][w] |= m;
        });
    } else if (CM == 2) {            // column-only kernel: vertical pass on B
        forcells<MR>([&](int r, int w) {
            u64 m = vand<RM>(B, r, w); M[r][w] = m; O[r][w] |= m;
        });
    } else {                         // row-only kernel: horizontal pass on B
        forcells<MR>([&](int r, int w) {
            u64 m = hand<CM>(B[r], w); M[r][w] = m; O[r][w] |= m;
        });
    }
    // ---- dilate + subtract ----
    if (DIL) {
        if (CM != 2 && RM != 2) {
            forcells<DHR>([&](int r, int w) { T[r][w] = hor<CM>(M[r], w); });
            forcells<BR>([&](int r, int w) { B[r][w] &= ~vor<RM>(T, r, w); });
        } else if (CM == 2) {
            forcells<BR>([&](int r, int w) { B[r][w] &= ~vor<RM>(M, r, w); });
        } else {
            forcells<BR>([&](int r, int w) { B[r][w] &= ~hor<CM>(M[r], w); });
        }
    }
}

// ---------------- phase 2: fused 8-step morphology + isolated-point ----------
__global__ __launch_bounds__(NTHR) void morph_kernel(const u64* __restrict__ packed,
                                                     float* __restrict__ out) {
    __shared__ u64 B[PR][PW];
    __shared__ u64 T[PR][PW];
    __shared__ u64 M[PR][PW];
    __shared__ u64 O[PR][PW];
    int tid = threadIdx.x;
    int ty = blockIdx.x, img = blockIdx.y;

    // zero B, M, O (pads stay zero forever -> zero boundary); T needs no init
    {
        u64* bf = &B[0][0]; u64* mf = &M[0][0]; u64* of = &O[0][0];
        for (int i = tid; i < PR * PW; i += NTHR) { bf[i] = 0; mf[i] = 0; of[i] = 0; }
    }
    __syncthreads();

    // load region: rows ty*TH-16 .. ty*TH+79 (clipped), full width
    const u64* pimg = packed + (size_t)img * HEIGHT * WPR;
    for (int idx = tid; idx < (TH + 32) * WPR; idx += NTHR) {
        int rr = idx >> 4, w = idx & 15;
        int gy = ty * TH - 16 + rr;
        if (gy >= 0 && gy < HEIGHT)
            B[rr + 1][w + 1] = pimg[(size_t)gy * WPR + w];
    }
    __syncthreads();

    // 8 structuring elements as (rowmask, colmask) rectangles; radii shrink 2/step
    morph_step<7, 7, 16, 15, 15, 14, true >(B, T, M, O);  // all ones
    morph_step<7, 6, 14, 13, 13, 12, true >(B, T, M, O);  // cols {1,2}
    morph_step<3, 7, 12, 11, 11, 10, true >(B, T, M, O);  // rows {0,1}
    morph_step<6, 6, 10,  9,  9,  8, true >(B, T, M, O);  // rows {1,2} x cols {1,2}
    morph_step<7, 2,  8,  7,  7,  6, true >(B, T, M, O);  // col {1}
    morph_step<2, 7,  6,  5,  5,  4, true >(B, T, M, O);  // row {1}
    morph_step<3, 2,  4,  3,  3,  2, true >(B, T, M, O);  // col {1}, rows {0,1}
    morph_step<2, 3,  2,  1,  1,  0, false>(B, T, M, O);  // row {1}, cols {0,1}

    // isolated-point: 3x3 popcount of O == 1 via carry-save (ones, sticky twos)
    forcells<0>([&](int r, int w) {
        u64 ones = 0;
        u64 twos = 0;
        #pragma unroll
        for (int dr = -1; dr <= 1; ++dr) {
            const u64* Ar = O[r + dr];
            u64 c  = Ar[w];
            u64 wv = (c << 1) | (Ar[w - 1] >> 63);
            u64 ev = (c >> 1) | (Ar[w + 1] << 63);
            twos |= ones & wv; ones ^= wv;
            twos |= ones & c;  ones ^= c;
            twos |= ones & ev; ones ^= ev;
        }
        T[r][w] = ones & ~twos;
    });

    // write float output, float4-vectorized, coalesced
    float* obase = out + ((size_t)img * HEIGHT + (size_t)ty * TH) * WIDTH;
    for (int idx = tid; idx < TH * (WIDTH / 4); idx += NTHR) {
        int row = idx >> 8;           // 256 float4 groups per row
        int q   = idx & 255;
        u64 word = T[17 + row][1 + (q >> 4)];
        int b = (q & 15) * 4;
        float4 v;
        v.x = (float)((word >> (b + 0)) & 1ULL);
        v.y = (float)((word >> (b + 1)) & 1ULL);
        v.z = (float)((word >> (b + 2)) & 1ULL);
        v.w = (float)((word >> (b + 3)) & 1ULL);
        *(float4*)(obase + (size_t)row * WIDTH + q * 4) = v;
    }
}

extern "C" void kernel_launch(void* const* d_in, const int* in_sizes, int n_in,
                              void* d_out, int out_size, void* d_ws, size_t ws_size,
                              hipStream_t stream) {
    const float* x = (const float*)d_in[0];
    float* out = (float*)d_out;
    u64* packed = (u64*)d_ws;   // NIMG*HEIGHT*WPR*8 = 2 MiB used

    hipLaunchKernelGGL(pack_kernel, dim3(NIMG * HEIGHT), dim3(256), 0, stream, x, packed);
    hipLaunchKernelGGL(morph_kernel, dim3(HEIGHT / TH, NIMG), dim3(NTHR), 0, stream,
                       packed, out);
}